// Round 3
// baseline (286.681 us; speedup 1.0000x reference)
//
#include <hip/hip_runtime.h>
#include <hip/hip_bf16.h>
#include <stdint.h>

#define DEV static __device__ __forceinline__

typedef float f32x4 __attribute__((ext_vector_type(4)));
typedef int   i32x4 __attribute__((ext_vector_type(4)));
typedef unsigned short u16x4 __attribute__((ext_vector_type(4)));
typedef __bf16 bf16x8 __attribute__((ext_vector_type(8)));

constexpr int Bb = 4, Ss = 2048, Ee = 512, Hh = 8, Dd = 64;
constexpr float SCALE = 0.125f;  // D^-0.5

DEV unsigned short f2bf(float f) {  // RNE f32->bf16 (no NaN path needed)
  unsigned u = __float_as_uint(f);
  u += 0x7fff + ((u >> 16) & 1);
  return (unsigned short)(u >> 16);
}
DEV float bf2f(unsigned short h) { return __uint_as_float(((unsigned)h) << 16); }

DEV void gload16(const void* g, void* l) {
  // async global->LDS, 16B per lane; LDS dest = wave-uniform base + lane*16
  __builtin_amdgcn_global_load_lds((__attribute__((address_space(1))) void*)(g),
                                   (__attribute__((address_space(3))) void*)(l), 16, 0, 0);
}

// ---------------- converts ----------------
__global__ void k_cvt(const float* __restrict__ src, unsigned short* __restrict__ dst, int n4) {
  int i = blockIdx.x * 256 + threadIdx.x;
  if (i >= n4) return;
  f32x4 v = *(const f32x4*)(src + (size_t)i * 4);
  u16x4 o;
#pragma unroll
  for (int j = 0; j < 4; ++j) o[j] = f2bf(v[j]);
  *(u16x4*)(dst + (size_t)i * 4) = o;
}

__global__ void k_mb(const float* __restrict__ bias, const int* __restrict__ mask,
                     unsigned short* __restrict__ mb, int n4) {
  int i = blockIdx.x * 256 + threadIdx.x;
  if (i >= n4) return;
  f32x4 v = *(const f32x4*)(bias + (size_t)i * 4);
  i32x4 m = *(const i32x4*)(mask + (size_t)i * 4);
  u16x4 o;
  const unsigned short NEG = f2bf(-1e38f);
#pragma unroll
  for (int j = 0; j < 4; ++j) o[j] = m[j] ? f2bf(v[j]) : NEG;
  *(u16x4*)(mb + (size_t)i * 4) = o;
}

// ---------------- GEMM (A[M][512] x Bw[N][512]^T), 128x128 tile, BK=32 ----------------
// MODE 0: QKV epilogue (scatter to q,k [B][H][S][D] and vt [B][H][D][S], bf16)
// MODE 1: f32 out epilogue (out[M][512] = acc + bo)
template <int MODE>
__global__ __launch_bounds__(256) void k_gemm(
    const unsigned short* __restrict__ A, const unsigned short* __restrict__ Bw,
    const float* __restrict__ b0, const float* __restrict__ b1, const float* __restrict__ b2,
    unsigned short* __restrict__ oq, unsigned short* __restrict__ ok,
    unsigned short* __restrict__ ovt, float* __restrict__ of32) {
  __shared__ unsigned short Asl[128 * 32];
  __shared__ unsigned short Bsl[128 * 32];
  const int tid = threadIdx.x;
  const int wave = tid >> 6, lane = tid & 63;
  const int l15 = lane & 15, lg = lane >> 4;
  const int brow = blockIdx.x, bcol = blockIdx.y;
  const int wm = (wave >> 1) * 64, wn = (wave & 1) * 64;

  f32x4 acc[4][4] = {};

  for (int k0 = 0; k0 < 512; k0 += 32) {
    __syncthreads();
#pragma unroll
    for (int rnd = 0; rnd < 2; ++rnd) {
      int vid = rnd * 256 + tid;
      int r = vid >> 2, c = vid & 3;
      gload16(A + (size_t)(brow * 128 + r) * 512 + k0 + c * 8,
              Asl + (size_t)(rnd * 256 + wave * 64) * 8);
      gload16(Bw + (size_t)(bcol * 128 + r) * 512 + k0 + c * 8,
              Bsl + (size_t)(rnd * 256 + wave * 64) * 8);
    }
    __syncthreads();
    bf16x8 af[4], bfr[4];
#pragma unroll
    for (int m = 0; m < 4; ++m) af[m] = *(const bf16x8*)(Asl + (wm + m * 16 + l15) * 32 + lg * 8);
#pragma unroll
    for (int n = 0; n < 4; ++n) bfr[n] = *(const bf16x8*)(Bsl + (wn + n * 16 + l15) * 32 + lg * 8);
#pragma unroll
    for (int m = 0; m < 4; ++m)
#pragma unroll
      for (int n = 0; n < 4; ++n)
        acc[m][n] = __builtin_amdgcn_mfma_f32_16x16x32_bf16(af[m], bfr[n], acc[m][n], 0, 0, 0);
  }

  if (MODE == 0) {
    const int Nbase = bcol * 128;
    const int mat = Nbase >> 9;        // 0=q,1=k,2=v (uniform per block)
    const int colb = Nbase & 511;
    const float* bp = (mat == 0) ? b0 : ((mat == 1) ? b1 : b2);
#pragma unroll
    for (int m = 0; m < 4; ++m)
#pragma unroll
      for (int n = 0; n < 4; ++n) {
        const int col = colb + wn + n * 16 + l15;  // within matrix, 0..511
        const int h = col >> 6, d = col & 63;
        const float bv = bp[col];
#pragma unroll
        for (int j = 0; j < 4; ++j) {
          const int M = brow * 128 + wm + m * 16 + lg * 4 + j;
          const int b = M >> 11, s = M & 2047;
          const unsigned short hv = f2bf(acc[m][n][j] + bv);
          if (mat == 0)
            oq[(((size_t)(b * Hh + h)) * Ss + s) * Dd + d] = hv;
          else if (mat == 1)
            ok[(((size_t)(b * Hh + h)) * Ss + s) * Dd + d] = hv;
          else
            ovt[(((size_t)(b * Hh + h)) * Dd + d) * Ss + s] = hv;  // V transposed
        }
      }
  } else {
#pragma unroll
    for (int m = 0; m < 4; ++m)
#pragma unroll
      for (int n = 0; n < 4; ++n) {
        const int col = bcol * 128 + wn + n * 16 + l15;
        const float bv = b0[col];
#pragma unroll
        for (int j = 0; j < 4; ++j) {
          const int M = brow * 128 + wm + m * 16 + lg * 4 + j;
          of32[(size_t)M * 512 + col] = acc[m][n][j] + bv;
        }
      }
  }
}

// ---------------- flash attention ----------------
// grid: (qt=16, bh=32); block 256 = 4 waves, each wave owns 32 q-rows.
// K tile 64 keys: Ksl [ks][key64][d32], Vsl [ks][d64][key32] (k-split keeps frag reads 8-way max)
__global__ __launch_bounds__(256) void k_attn(
    const unsigned short* __restrict__ q, const unsigned short* __restrict__ k,
    const unsigned short* __restrict__ vt, const unsigned short* __restrict__ mb,
    unsigned short* __restrict__ att) {
  __shared__ unsigned short Ksl[2 * 64 * 32];
  __shared__ unsigned short Vsl[2 * 64 * 32];
  __shared__ unsigned short Psl[4][32 * 72];  // per-wave P, pad to 72 (16B-aligned rows)
  const int tid = threadIdx.x;
  const int wave = tid >> 6, lane = tid & 63;
  const int l15 = lane & 15, lg = lane >> 4;
  const int qt = blockIdx.x, bh = blockIdx.y;
  const int b = bh >> 3, h = bh & 7;
  const size_t qkb = (size_t)bh * Ss * Dd;
  const size_t vtb = (size_t)bh * Dd * Ss;
  const int q0 = qt * 128 + wave * 32;

  bf16x8 qf[2][2];  // [m][ks] Q rows hoisted into regs
#pragma unroll
  for (int m = 0; m < 2; ++m)
#pragma unroll
    for (int ks = 0; ks < 2; ++ks)
      qf[m][ks] = *(const bf16x8*)(q + qkb + (size_t)(q0 + m * 16 + l15) * Dd + ks * 32 + lg * 8);

  f32x4 accO[2][4] = {};
  float mrow[2][4], lrow[2][4];
#pragma unroll
  for (int m = 0; m < 2; ++m)
#pragma unroll
    for (int j = 0; j < 4; ++j) { mrow[m][j] = -INFINITY; lrow[m][j] = 0.f; }

  for (int t = 0; t < 32; ++t) {
    const int key0 = t * 64;
    __syncthreads();
#pragma unroll
    for (int rnd = 0; rnd < 2; ++rnd) {
      int v2 = rnd * 256 + tid;
      int ks = v2 >> 8, r = (v2 >> 2) & 63, c = v2 & 3;
      gload16(k + qkb + (size_t)(key0 + r) * Dd + ks * 32 + c * 8,
              Ksl + (rnd * 256 + wave * 64) * 8);
    }
#pragma unroll
    for (int rnd = 0; rnd < 2; ++rnd) {
      int v2 = rnd * 256 + tid;
      int ks = v2 >> 8, r = (v2 >> 2) & 63, c = v2 & 3;
      gload16(vt + vtb + (size_t)r * Ss + key0 + ks * 32 + c * 8,
              Vsl + (rnd * 256 + wave * 64) * 8);
    }
    __syncthreads();

    f32x4 sc[2][4] = {};
#pragma unroll
    for (int ks = 0; ks < 2; ++ks) {
      bf16x8 kf[4];
#pragma unroll
      for (int n = 0; n < 4; ++n)
        kf[n] = *(const bf16x8*)(Ksl + ks * 2048 + (n * 16 + l15) * 32 + lg * 8);
#pragma unroll
      for (int m = 0; m < 2; ++m)
#pragma unroll
        for (int n = 0; n < 4; ++n)
          sc[m][n] = __builtin_amdgcn_mfma_f32_16x16x32_bf16(qf[m][ks], kf[n], sc[m][n], 0, 0, 0);
    }

#pragma unroll
    for (int m = 0; m < 2; ++m) {
#pragma unroll
      for (int n = 0; n < 4; ++n)
#pragma unroll
        for (int j = 0; j < 4; ++j) {
          const int row = q0 + m * 16 + lg * 4 + j;
          const float bias = bf2f(mb[(size_t)(b * Ss + row) * Ss + key0 + n * 16 + l15]);
          sc[m][n][j] = sc[m][n][j] * SCALE + bias;
        }
      float cj[4];
#pragma unroll
      for (int j = 0; j < 4; ++j) {
        float mx = fmaxf(fmaxf(sc[m][0][j], sc[m][1][j]), fmaxf(sc[m][2][j], sc[m][3][j]));
        mx = fmaxf(mx, __shfl_xor(mx, 1));
        mx = fmaxf(mx, __shfl_xor(mx, 2));
        mx = fmaxf(mx, __shfl_xor(mx, 4));
        mx = fmaxf(mx, __shfl_xor(mx, 8));
        const float mnew = fmaxf(mrow[m][j], mx);
        const float c = __expf(mrow[m][j] - mnew);
        mrow[m][j] = mnew;
        float rs = 0.f;
#pragma unroll
        for (int n = 0; n < 4; ++n) {
          const float pv = __expf(sc[m][n][j] - mnew);
          sc[m][n][j] = pv;  // reuse storage as P
          rs += pv;
        }
        rs += __shfl_xor(rs, 1);
        rs += __shfl_xor(rs, 2);
        rs += __shfl_xor(rs, 4);
        rs += __shfl_xor(rs, 8);
        lrow[m][j] = lrow[m][j] * c + rs;
        cj[j] = c;
      }
#pragma unroll
      for (int n = 0; n < 4; ++n)
#pragma unroll
        for (int j = 0; j < 4; ++j) {
          accO[m][n][j] *= cj[j];
          Psl[wave][(m * 16 + lg * 4 + j) * 72 + n * 16 + l15] = f2bf(sc[m][n][j]);
        }
    }
    asm volatile("s_waitcnt lgkmcnt(0)" ::: "memory");  // wave-local P write->read
#pragma unroll
    for (int ks = 0; ks < 2; ++ks) {
      bf16x8 vf[4], pf[2];
#pragma unroll
      for (int n = 0; n < 4; ++n)
        vf[n] = *(const bf16x8*)(Vsl + ks * 2048 + (n * 16 + l15) * 32 + lg * 8);
#pragma unroll
      for (int m = 0; m < 2; ++m)
        pf[m] = *(const bf16x8*)(&Psl[wave][(m * 16 + l15) * 72 + ks * 32 + lg * 8]);
#pragma unroll
      for (int m = 0; m < 2; ++m)
#pragma unroll
        for (int n = 0; n < 4; ++n)
          accO[m][n] = __builtin_amdgcn_mfma_f32_16x16x32_bf16(pf[m], vf[n], accO[m][n], 0, 0, 0);
    }
  }

#pragma unroll
  for (int m = 0; m < 2; ++m)
#pragma unroll
    for (int j = 0; j < 4; ++j) {
      const float invl = 1.0f / lrow[m][j];
      const int row = q0 + m * 16 + lg * 4 + j;
#pragma unroll
      for (int n = 0; n < 4; ++n) {
        const int d = n * 16 + l15;
        att[((size_t)b * Ss + row) * Ee + h * Dd + d] = f2bf(accO[m][n][j] * invl);
      }
    }
}

extern "C" void kernel_launch(void* const* d_in, const int* in_sizes, int n_in,
                              void* d_out, int out_size, void* d_ws, size_t ws_size,
                              hipStream_t stream) {
  const float* x  = (const float*)d_in[0];
  const float* eb = (const float*)d_in[1];
  const int*   am = (const int*)d_in[2];
  const float* Wq = (const float*)d_in[3];
  const float* bq = (const float*)d_in[4];
  const float* Wk = (const float*)d_in[5];
  const float* bk = (const float*)d_in[6];
  const float* Wv = (const float*)d_in[7];
  const float* bv = (const float*)d_in[8];
  const float* Wo = (const float*)d_in[9];
  const float* bo = (const float*)d_in[10];
  float* out = (float*)d_out;

  unsigned short* xb   = (unsigned short*)d_ws;              // [8192][512]
  unsigned short* wqkv = xb + (size_t)8192 * 512;            // [1536][512]
  unsigned short* wo   = wqkv + (size_t)1536 * 512;          // [512][512]
  unsigned short* qb   = wo + (size_t)512 * 512;             // [B][H][S][D]
  unsigned short* kb   = qb + (size_t)Bb * Hh * Ss * Dd;     // [B][H][S][D]
  unsigned short* vtb  = kb + (size_t)Bb * Hh * Ss * Dd;     // [B][H][D][S]
  unsigned short* attb = vtb + (size_t)Bb * Hh * Ss * Dd;    // [8192][512]
  unsigned short* mbb  = attb + (size_t)8192 * 512;          // [B][S][S]

  k_cvt<<<4096, 256, 0, stream>>>(x, xb, 8192 * 512 / 4);
  k_cvt<<<256, 256, 0, stream>>>(Wq, wqkv, 512 * 512 / 4);
  k_cvt<<<256, 256, 0, stream>>>(Wk, wqkv + (size_t)512 * 512, 512 * 512 / 4);
  k_cvt<<<256, 256, 0, stream>>>(Wv, wqkv + (size_t)1024 * 512, 512 * 512 / 4);
  k_cvt<<<256, 256, 0, stream>>>(Wo, wo, 512 * 512 / 4);
  k_mb<<<16384, 256, 0, stream>>>(eb, am, mbb, Bb * Ss * Ss / 4);

  dim3 blk(256);
  dim3 g1(64, 12);
  k_gemm<0><<<g1, blk, 0, stream>>>(xb, wqkv, bq, bk, bv, qb, kb, vtb, nullptr);
  dim3 g2(16, 32);
  k_attn<<<g2, blk, 0, stream>>>(qb, kb, vtb, mbb, attb);
  dim3 g3(64, 4);
  k_gemm<1><<<g3, blk, 0, stream>>>(attb, wo, bo, nullptr, nullptr, nullptr, nullptr, nullptr, out);
}

// Round 4
// 200.564 us; speedup vs baseline: 1.4294x; 1.4294x over previous
//
#include <hip/hip_runtime.h>
#include <hip/hip_bf16.h>
#include <stdint.h>

#define DEV static __device__ __forceinline__

typedef float f32x4 __attribute__((ext_vector_type(4)));
typedef int   i32x4 __attribute__((ext_vector_type(4)));
typedef unsigned short u16x4 __attribute__((ext_vector_type(4)));
typedef __bf16 bf16x8 __attribute__((ext_vector_type(8)));

constexpr int Bb = 4, Ss = 2048, Ee = 512, Hh = 8, Dd = 64;

DEV unsigned short f2bf(float f) {  // RNE f32->bf16 (no NaN path needed)
  unsigned u = __float_as_uint(f);
  u += 0x7fff + ((u >> 16) & 1);
  return (unsigned short)(u >> 16);
}
DEV float bf2f(unsigned short h) { return __uint_as_float(((unsigned)h) << 16); }

DEV void gload16(const void* g, void* l) {
  // async global->LDS, 16B per lane; LDS dest = wave-uniform base + lane*16
  __builtin_amdgcn_global_load_lds((__attribute__((address_space(1))) void*)(g),
                                   (__attribute__((address_space(3))) void*)(l), 16, 0, 0);
}

// ---------------- converts ----------------
__global__ void k_cvt(const float* __restrict__ src, unsigned short* __restrict__ dst, int n4) {
  int i = blockIdx.x * 256 + threadIdx.x;
  if (i >= n4) return;
  f32x4 v = *(const f32x4*)(src + (size_t)i * 4);
  u16x4 o;
#pragma unroll
  for (int j = 0; j < 4; ++j) o[j] = f2bf(v[j]);
  *(u16x4*)(dst + (size_t)i * 4) = o;
}

__global__ void k_mb(const float* __restrict__ bias, const int* __restrict__ mask,
                     unsigned short* __restrict__ mb, int n4) {
  int i = blockIdx.x * 256 + threadIdx.x;
  if (i >= n4) return;
  f32x4 v = *(const f32x4*)(bias + (size_t)i * 4);
  i32x4 m = *(const i32x4*)(mask + (size_t)i * 4);
  u16x4 o;
  const unsigned short NEG = f2bf(-1e38f);
#pragma unroll
  for (int j = 0; j < 4; ++j) o[j] = m[j] ? f2bf(v[j]) : NEG;
  *(u16x4*)(mb + (size_t)i * 4) = o;
}

// ---------------- GEMM (A[M][512] x Bw[N][512]^T), 128x128 tile, BK=32 ----------------
// MODE 0: QKV epilogue (scatter to q,k [B][H][S][D] and vt [B][H][D][S], bf16; q pre-scaled)
// MODE 1: f32 out epilogue (out[M][512] = acc + bo)
template <int MODE>
__global__ __launch_bounds__(256) void k_gemm(
    const unsigned short* __restrict__ A, const unsigned short* __restrict__ Bw,
    const float* __restrict__ b0, const float* __restrict__ b1, const float* __restrict__ b2,
    unsigned short* __restrict__ oq, unsigned short* __restrict__ ok,
    unsigned short* __restrict__ ovt, float* __restrict__ of32) {
  __shared__ unsigned short Asl[128 * 32];
  __shared__ unsigned short Bsl[128 * 32];
  const int tid = threadIdx.x;
  const int wave = tid >> 6, lane = tid & 63;
  const int l15 = lane & 15, lg = lane >> 4;
  const int brow = blockIdx.x, bcol = blockIdx.y;
  const int wm = (wave >> 1) * 64, wn = (wave & 1) * 64;

  f32x4 acc[4][4] = {};

  for (int k0 = 0; k0 < 512; k0 += 32) {
    __syncthreads();
#pragma unroll
    for (int rnd = 0; rnd < 2; ++rnd) {
      int vid = rnd * 256 + tid;
      int r = vid >> 2, c = vid & 3;
      gload16(A + (size_t)(brow * 128 + r) * 512 + k0 + c * 8,
              Asl + (size_t)(rnd * 256 + wave * 64) * 8);
      gload16(Bw + (size_t)(bcol * 128 + r) * 512 + k0 + c * 8,
              Bsl + (size_t)(rnd * 256 + wave * 64) * 8);
    }
    __syncthreads();
    bf16x8 af[4], bfr[4];
#pragma unroll
    for (int m = 0; m < 4; ++m) af[m] = *(const bf16x8*)(Asl + (wm + m * 16 + l15) * 32 + lg * 8);
#pragma unroll
    for (int n = 0; n < 4; ++n) bfr[n] = *(const bf16x8*)(Bsl + (wn + n * 16 + l15) * 32 + lg * 8);
#pragma unroll
    for (int m = 0; m < 4; ++m)
#pragma unroll
      for (int n = 0; n < 4; ++n)
        acc[m][n] = __builtin_amdgcn_mfma_f32_16x16x32_bf16(af[m], bfr[n], acc[m][n], 0, 0, 0);
  }

  if (MODE == 0) {
    const int Nbase = bcol * 128;
    const int mat = Nbase >> 9;        // 0=q,1=k,2=v (uniform per block)
    const int colb = Nbase & 511;
    const float* bp = (mat == 0) ? b0 : ((mat == 1) ? b1 : b2);
#pragma unroll
    for (int m = 0; m < 4; ++m)
#pragma unroll
      for (int n = 0; n < 4; ++n) {
        const int col = colb + wn + n * 16 + l15;  // within matrix, 0..511
        const int h = col >> 6, d = col & 63;
        const float bv = bp[col];
#pragma unroll
        for (int j = 0; j < 4; ++j) {
          const int M = brow * 128 + wm + m * 16 + lg * 4 + j;
          const int b = M >> 11, s = M & 2047;
          float outv = acc[m][n][j] + bv;
          if (mat == 0) outv *= 0.125f;  // fold softmax scale into q (exact pow2)
          const unsigned short hv = f2bf(outv);
          if (mat == 0)
            oq[(((size_t)(b * Hh + h)) * Ss + s) * Dd + d] = hv;
          else if (mat == 1)
            ok[(((size_t)(b * Hh + h)) * Ss + s) * Dd + d] = hv;
          else
            ovt[(((size_t)(b * Hh + h)) * Dd + d) * Ss + s] = hv;  // V transposed
        }
      }
  } else {
#pragma unroll
    for (int m = 0; m < 4; ++m)
#pragma unroll
      for (int n = 0; n < 4; ++n) {
        const int col = bcol * 128 + wn + n * 16 + l15;
        const float bv = b0[col];
#pragma unroll
        for (int j = 0; j < 4; ++j) {
          const int M = brow * 128 + wm + m * 16 + lg * 4 + j;
          of32[(size_t)M * 512 + col] = acc[m][n][j] + bv;
        }
      }
  }
}

// ---------------- flash attention (v2: dbuf K/V, 1 barrier/iter, 4 blocks/CU) ----------
// grid: (qt=32, bh=32); block 256 = 4 waves, each wave owns 16 q-rows.
// K tile 64 keys: Ksl [buf][ks][key64][d32], Vsl [buf][ks][d64][key32]
// Psl [wave][16*64] XOR-swizzled (u16 idx ^= (row&7)<<3)
__global__ __launch_bounds__(256, 4) void k_attn(
    const unsigned short* __restrict__ q, const unsigned short* __restrict__ k,
    const unsigned short* __restrict__ vt, const unsigned short* __restrict__ mb,
    unsigned short* __restrict__ att) {
  __shared__ unsigned short Ksl[2][4096];
  __shared__ unsigned short Vsl[2][4096];
  __shared__ unsigned short Psl[4][1024];
  const int tid = threadIdx.x;
  const int wave = tid >> 6, lane = tid & 63;
  const int l15 = lane & 15, lg = lane >> 4;
  const int qt = blockIdx.x, bh = blockIdx.y;
  const int b = bh >> 3, h = bh & 7;
  const size_t qkb = (size_t)bh * Ss * Dd;
  const size_t vtbase = (size_t)bh * Dd * Ss;
  const int q0 = qt * 64 + wave * 16;

  bf16x8 qf[2];  // Q rows hoisted into regs (pre-scaled by 1/8 at projection)
#pragma unroll
  for (int ks = 0; ks < 2; ++ks)
    qf[ks] = *(const bf16x8*)(q + qkb + (size_t)(q0 + l15) * Dd + ks * 32 + lg * 8);

  size_t mbbase[4];  // per-j bias row base (constant across tiles)
#pragma unroll
  for (int j = 0; j < 4; ++j)
    mbbase[j] = ((size_t)b * Ss + (size_t)(q0 + lg * 4 + j)) * Ss + l15;

  f32x4 accO[4] = {};
  float mrow[4], lrow[4];
#pragma unroll
  for (int j = 0; j < 4; ++j) { mrow[j] = -INFINITY; lrow[j] = 0.f; }

  auto stage = [&](int buf, int t) {
    const int key0 = t * 64;
#pragma unroll
    for (int rnd = 0; rnd < 2; ++rnd) {
      int v2 = rnd * 256 + tid;
      int ks = v2 >> 8, r = (v2 >> 2) & 63, c = v2 & 3;
      gload16(k + qkb + (size_t)(key0 + r) * Dd + ks * 32 + c * 8,
              &Ksl[buf][(rnd * 256 + wave * 64) * 8]);
    }
#pragma unroll
    for (int rnd = 0; rnd < 2; ++rnd) {
      int v2 = rnd * 256 + tid;
      int ks = v2 >> 8, r = (v2 >> 2) & 63, c = v2 & 3;
      gload16(vt + vtbase + (size_t)r * Ss + key0 + ks * 32 + c * 8,
              &Vsl[buf][(rnd * 256 + wave * 64) * 8]);
    }
  };
  stage(0, 0);

  for (int t = 0; t < 32; ++t) {
    const int cur = t & 1;
    const int key0 = t * 64;
    __syncthreads();  // tile t staged (vmcnt drained); prior reads of buf[cur] done

    // bias loads for this tile (used after QK MFMA -> latency hidden)
    unsigned short bvv[4][4];
#pragma unroll
    for (int n = 0; n < 4; ++n)
#pragma unroll
      for (int j = 0; j < 4; ++j)
        bvv[n][j] = mb[mbbase[j] + key0 + n * 16];

    if (t < 31) stage(cur ^ 1, t + 1);  // prefetch next tile into other buffer

    f32x4 sc[4] = {};
#pragma unroll
    for (int ks = 0; ks < 2; ++ks) {
      bf16x8 kf[4];
#pragma unroll
      for (int n = 0; n < 4; ++n)
        kf[n] = *(const bf16x8*)(&Ksl[cur][ks * 2048 + (n * 16 + l15) * 32 + lg * 8]);
#pragma unroll
      for (int n = 0; n < 4; ++n)
        sc[n] = __builtin_amdgcn_mfma_f32_16x16x32_bf16(qf[ks], kf[n], sc[n], 0, 0, 0);
    }

    float cj[4];
#pragma unroll
    for (int j = 0; j < 4; ++j) {
#pragma unroll
      for (int n = 0; n < 4; ++n) sc[n][j] += bf2f(bvv[n][j]);
      float mx = fmaxf(fmaxf(sc[0][j], sc[1][j]), fmaxf(sc[2][j], sc[3][j]));
      mx = fmaxf(mx, __shfl_xor(mx, 1));
      mx = fmaxf(mx, __shfl_xor(mx, 2));
      mx = fmaxf(mx, __shfl_xor(mx, 4));
      mx = fmaxf(mx, __shfl_xor(mx, 8));
      const float mnew = fmaxf(mrow[j], mx);
      const float c = __expf(mrow[j] - mnew);
      mrow[j] = mnew;
      float rs = 0.f;
#pragma unroll
      for (int n = 0; n < 4; ++n) {
        const float pv = __expf(sc[n][j] - mnew);
        sc[n][j] = pv;  // reuse storage as P
        rs += pv;
      }
      rs += __shfl_xor(rs, 1);
      rs += __shfl_xor(rs, 2);
      rs += __shfl_xor(rs, 4);
      rs += __shfl_xor(rs, 8);
      lrow[j] = lrow[j] * c + rs;
      cj[j] = c;
    }

#pragma unroll
    for (int n = 0; n < 4; ++n)
#pragma unroll
      for (int j = 0; j < 4; ++j) {
        accO[n][j] *= cj[j];
        const int row = lg * 4 + j;
        Psl[wave][(row * 64 + n * 16 + l15) ^ ((row & 7) << 3)] = f2bf(sc[n][j]);
      }
    asm volatile("s_waitcnt lgkmcnt(0)" ::: "memory");  // wave-local P write->read

#pragma unroll
    for (int ks = 0; ks < 2; ++ks) {
      bf16x8 pf = *(const bf16x8*)(&Psl[wave][(l15 * 64 + ks * 32 + lg * 8) ^ ((l15 & 7) << 3)]);
      bf16x8 vf[4];
#pragma unroll
      for (int n = 0; n < 4; ++n)
        vf[n] = *(const bf16x8*)(&Vsl[cur][ks * 2048 + (n * 16 + l15) * 32 + lg * 8]);
#pragma unroll
      for (int n = 0; n < 4; ++n)
        accO[n] = __builtin_amdgcn_mfma_f32_16x16x32_bf16(pf, vf[n], accO[n], 0, 0, 0);
    }
  }

#pragma unroll
  for (int j = 0; j < 4; ++j) {
    const float invl = 1.0f / lrow[j];
    const int row = q0 + lg * 4 + j;
#pragma unroll
    for (int n = 0; n < 4; ++n)
      att[((size_t)b * Ss + row) * Ee + h * Dd + n * 16 + l15] = f2bf(accO[n][j] * invl);
  }
}

extern "C" void kernel_launch(void* const* d_in, const int* in_sizes, int n_in,
                              void* d_out, int out_size, void* d_ws, size_t ws_size,
                              hipStream_t stream) {
  const float* x  = (const float*)d_in[0];
  const float* eb = (const float*)d_in[1];
  const int*   am = (const int*)d_in[2];
  const float* Wq = (const float*)d_in[3];
  const float* bq = (const float*)d_in[4];
  const float* Wk = (const float*)d_in[5];
  const float* bk = (const float*)d_in[6];
  const float* Wv = (const float*)d_in[7];
  const float* bv = (const float*)d_in[8];
  const float* Wo = (const float*)d_in[9];
  const float* bo = (const float*)d_in[10];
  float* out = (float*)d_out;

  unsigned short* xb   = (unsigned short*)d_ws;              // [8192][512]
  unsigned short* wqkv = xb + (size_t)8192 * 512;            // [1536][512]
  unsigned short* wo   = wqkv + (size_t)1536 * 512;          // [512][512]
  unsigned short* qb   = wo + (size_t)512 * 512;             // [B][H][S][D]
  unsigned short* kb   = qb + (size_t)Bb * Hh * Ss * Dd;     // [B][H][S][D]
  unsigned short* vtb  = kb + (size_t)Bb * Hh * Ss * Dd;     // [B][H][D][S]
  unsigned short* attb = vtb + (size_t)Bb * Hh * Ss * Dd;    // [8192][512]
  unsigned short* mbb  = attb + (size_t)8192 * 512;          // [B][S][S]

  k_cvt<<<4096, 256, 0, stream>>>(x, xb, 8192 * 512 / 4);
  k_cvt<<<256, 256, 0, stream>>>(Wq, wqkv, 512 * 512 / 4);
  k_cvt<<<256, 256, 0, stream>>>(Wk, wqkv + (size_t)512 * 512, 512 * 512 / 4);
  k_cvt<<<256, 256, 0, stream>>>(Wv, wqkv + (size_t)1024 * 512, 512 * 512 / 4);
  k_cvt<<<256, 256, 0, stream>>>(Wo, wo, 512 * 512 / 4);
  k_mb<<<16384, 256, 0, stream>>>(eb, am, mbb, Bb * Ss * Ss / 4);

  dim3 blk(256);
  dim3 g1(64, 12);
  k_gemm<0><<<g1, blk, 0, stream>>>(xb, wqkv, bq, bk, bv, qb, kb, vtb, nullptr);
  dim3 g2(32, 32);
  k_attn<<<g2, blk, 0, stream>>>(qb, kb, vtb, mbb, attb);
  dim3 g3(64, 4);
  k_gemm<1><<<g3, blk, 0, stream>>>(attb, wo, bo, nullptr, nullptr, nullptr, nullptr, nullptr, out);
}